// Round 1
// baseline (630.469 us; speedup 1.0000x reference)
//
#include <hip/hip_runtime.h>

#define B_   2
#define L_   2048
#define DM   2048
#define H_   16
#define DH   128
#define M_   (B_*L_)        // 4096
#define NQKV (3*DM)         // 6144

typedef __attribute__((ext_vector_type(8))) short short8;
typedef __attribute__((ext_vector_type(4))) float f32x4;
typedef __attribute__((ext_vector_type(4))) unsigned short ushort4_t;

static __device__ __forceinline__ unsigned short f2b(float f) {
    union { float f; unsigned int u; } v; v.f = f;
    unsigned int u = v.u + 0x7fffu + ((v.u >> 16) & 1u);
    return (unsigned short)(u >> 16);
}
static __device__ __forceinline__ float b2f(unsigned short s) {
    union { unsigned int u; float f; } v; v.u = ((unsigned int)s) << 16;
    return v.f;
}
static __device__ __forceinline__ void async16(const void* g, void* l) {
    __builtin_amdgcn_global_load_lds(
        (const __attribute__((address_space(1))) unsigned int*)g,
        (__attribute__((address_space(3))) unsigned int*)l, 16, 0, 0);
}

// ---------------- fp32 -> bf16 conversion of x, Wq|Wk|Wv (concat), Wo ----------------
__global__ void cvt_kernel(const float* __restrict__ x,
                           const float* __restrict__ wq, const float* __restrict__ wk,
                           const float* __restrict__ wv, const float* __restrict__ wo,
                           unsigned short* __restrict__ xb,
                           unsigned short* __restrict__ wqkv,
                           unsigned short* __restrict__ wob) {
    const long MD = (long)M_ * DM;       // 8,388,608
    const long DD = (long)DM * DM;       // 4,194,304
    const long total4 = (MD + 4 * DD) / 4;
    for (long i = (long)blockIdx.x * blockDim.x + threadIdx.x; i < total4;
         i += (long)gridDim.x * blockDim.x) {
        long base = i * 4;
        const float* src; unsigned short* dst;
        if (base < MD) { src = x + base; dst = xb + base; }
        else {
            long r = base - MD;
            int w = (int)(r / DD);
            long off = r - (long)w * DD;
            src = (w == 0 ? wq : (w == 1 ? wk : (w == 2 ? wv : wo))) + off;
            dst = (w < 3) ? (wqkv + r) : (wob + off);
        }
        float4 v = *(const float4*)src;
        ushort4_t o;
        o.x = f2b(v.x); o.y = f2b(v.y); o.z = f2b(v.z); o.w = f2b(v.w);
        *(ushort4_t*)dst = o;
    }
}

// ---------------- QKV projection GEMM: C(4096 x 6144) = xb * wqkv^T ----------------
// epilogue scatters bf16 into qb/kb/vb laid out [b, h, l, dh]
__global__ __launch_bounds__(256, 2) void gemm_qkv_kernel(
        const unsigned short* __restrict__ A,    // 4096 x 2048 bf16
        const unsigned short* __restrict__ Bm,   // 6144 x 2048 bf16 (N x K, row-major)
        unsigned short* __restrict__ qb, unsigned short* __restrict__ kb,
        unsigned short* __restrict__ vb) {
    __shared__ __align__(16) unsigned short As[128 * 64];
    __shared__ __align__(16) unsigned short Bs[128 * 64];
    const int tid = threadIdx.x;
    const int wave = tid >> 6, lane = tid & 63, quad = lane >> 4, lq = lane & 15;
    const int wm = wave & 1, wn = wave >> 1;
    const int m0 = blockIdx.y * 128, n0 = blockIdx.x * 128;

    f32x4 acc[4][4];
    const f32x4 zero4 = {0.f, 0.f, 0.f, 0.f};
    #pragma unroll
    for (int i = 0; i < 4; i++)
        #pragma unroll
        for (int j = 0; j < 4; j++) acc[i][j] = zero4;

    const int row_l = lane >> 3;
    const int col_l = (lane & 7) * 8;
    for (int k0 = 0; k0 < DM; k0 += 64) {
        __syncthreads();
        #pragma unroll
        for (int c = 0; c < 4; c++) {
            int chunk = wave * 4 + c;
            int row = chunk * 8 + row_l;
            async16(A  + (long)(m0 + row) * DM + k0 + col_l, &As[chunk * 512]);
            async16(Bm + (long)(n0 + row) * DM + k0 + col_l, &Bs[chunk * 512]);
        }
        __syncthreads();
        #pragma unroll
        for (int s = 0; s < 2; s++) {
            const int kk = s * 32 + quad * 8;
            short8 af[4], bf[4];
            #pragma unroll
            for (int i = 0; i < 4; i++)
                af[i] = *(const short8*)&As[(wm * 64 + i * 16 + lq) * 64 + kk];
            #pragma unroll
            for (int j = 0; j < 4; j++)
                bf[j] = *(const short8*)&Bs[(wn * 64 + j * 16 + lq) * 64 + kk];
            #pragma unroll
            for (int i = 0; i < 4; i++)
                #pragma unroll
                for (int j = 0; j < 4; j++)
                    acc[i][j] = __builtin_amdgcn_mfma_f32_16x16x32_bf16(af[i], bf[j], acc[i][j], 0, 0, 0);
        }
    }
    const int which = n0 >> 11;                 // 0=Q, 1=K, 2=V (128 | 2048 so no crossing)
    unsigned short* dst = which == 0 ? qb : (which == 1 ? kb : vb);
    #pragma unroll
    for (int i = 0; i < 4; i++) {
        #pragma unroll
        for (int j = 0; j < 4; j++) {
            int n = n0 + wn * 64 + j * 16 + lq;
            int o = n & (DM - 1);
            int h = o >> 7, dh = o & 127;
            #pragma unroll
            for (int r = 0; r < 4; r++) {
                int m = m0 + wm * 64 + i * 16 + quad * 4 + r;
                int b = m >> 11, l = m & (L_ - 1);
                dst[((long)(b * H_ + h) * L_ + l) * DH + dh] = f2b(acc[i][j][r]);
            }
        }
    }
}

// ---------------- RoPE in-place on qb and kb ----------------
__global__ void rope_kernel(unsigned short* __restrict__ qb,
                            unsigned short* __restrict__ kb,
                            const int* __restrict__ tp) {
    const long PAIRS = (long)B_ * H_ * L_ * (DH / 2);   // 4,194,304
    const float lg = 0.20762050593046016f;               // log2(10000)/64
    for (long i = (long)blockIdx.x * blockDim.x + threadIdx.x; i < 2 * PAIRS;
         i += (long)gridDim.x * blockDim.x) {
        unsigned short* base = (i < PAIRS) ? qb : kb;
        long p = (i < PAIRS) ? i : i - PAIRS;
        int c  = (int)(p & 63);
        int l  = (int)((p >> 6) & (L_ - 1));
        int bh = (int)(p >> 17);
        int b  = bh >> 4;
        int pos = tp[b * L_ + l];
        float ang = (float)pos * exp2f(-lg * (float)c);
        float sn = sinf(ang), cs = cosf(ang);
        unsigned int* pp = (unsigned int*)base + p;
        unsigned int val = *pp;
        float x1 = b2f((unsigned short)(val & 0xffffu));
        float x2 = b2f((unsigned short)(val >> 16));
        float o1 = x1 * cs - x2 * sn;
        float o2 = x1 * sn + x2 * cs;
        *pp = (unsigned int)f2b(o1) | ((unsigned int)f2b(o2) << 16);
    }
}

// ---------------- flash attention (causal), MFMA ----------------
// grid: (B*H, L/64); block 256 = 4 waves, each wave owns 16 q-rows
__global__ __launch_bounds__(256, 2) void attn_kernel(
        const unsigned short* __restrict__ qb,
        const unsigned short* __restrict__ kb,
        const unsigned short* __restrict__ vb,
        unsigned short* __restrict__ ab) {
    __shared__ __align__(16) unsigned short Ks[64 * 128];
    __shared__ __align__(16) unsigned short Vt[128 * 72];   // V^T, row stride 72
    __shared__ __align__(16) unsigned short Pl[4][16 * 64];
    const int tid = threadIdx.x;
    const int wave = tid >> 6, lane = tid & 63, quad = lane >> 4, lq = lane & 15;
    const int bh = blockIdx.x, qt = blockIdx.y;
    const int b = bh >> 4, h = bh & 15;
    const long plane = (long)bh * L_ * DH;

    const int qrow = qt * 64 + wave * 16 + lq;
    short8 aQ[4];
    #pragma unroll
    for (int c = 0; c < 4; c++)
        aQ[c] = *(const short8*)(qb + plane + (long)qrow * DH + c * 32 + quad * 8);

    const f32x4 zero4 = {0.f, 0.f, 0.f, 0.f};
    f32x4 o[8];
    #pragma unroll
    for (int jj = 0; jj < 8; jj++) o[jj] = zero4;
    float m_i[4], l_i[4];
    #pragma unroll
    for (int r = 0; r < 4; r++) { m_i[r] = -__builtin_inff(); l_i[r] = 0.0f; }

    const float scale = 0.08838834764831845f;   // 1/sqrt(128)

    for (int kt = 0; kt <= qt; kt++) {
        __syncthreads();
        const long kbase = plane + (long)kt * 64 * DH;
        #pragma unroll
        for (int c = 0; c < 4; c++) {
            int chunk = wave * 4 + c;
            async16(kb + kbase + chunk * 512 + lane * 8, &Ks[chunk * 512]);
        }
        #pragma unroll
        for (int p = 0; p < 4; p++) {                 // V tile, transposed into LDS
            int flat = p * 2048 + tid * 8;
            int l = flat >> 7, d0 = flat & 127;
            short8 vv = *(const short8*)(vb + kbase + flat);
            #pragma unroll
            for (int i2 = 0; i2 < 8; i2++)
                Vt[(d0 + i2) * 72 + l] = (unsigned short)vv[i2];
        }
        __syncthreads();

        f32x4 s[4];
        #pragma unroll
        for (int j = 0; j < 4; j++) {
            s[j] = zero4;
            #pragma unroll
            for (int c = 0; c < 4; c++) {
                short8 bk = *(const short8*)&Ks[(j * 16 + lq) * 128 + c * 32 + quad * 8];
                s[j] = __builtin_amdgcn_mfma_f32_16x16x32_bf16(aQ[c], bk, s[j], 0, 0, 0);
            }
        }
        const bool diag = (kt == qt);
        #pragma unroll
        for (int j = 0; j < 4; j++) {
            int key = kt * 64 + j * 16 + lq;
            #pragma unroll
            for (int r = 0; r < 4; r++) {
                float v = s[j][r] * scale;
                int row = qt * 64 + wave * 16 + quad * 4 + r;
                if (diag && key > row) v = -__builtin_inff();
                s[j][r] = v;
            }
        }
        float alpha[4];
        #pragma unroll
        for (int r = 0; r < 4; r++) {
            float v = fmaxf(fmaxf(s[0][r], s[1][r]), fmaxf(s[2][r], s[3][r]));
            v = fmaxf(v, __shfl_xor(v, 1, 64));
            v = fmaxf(v, __shfl_xor(v, 2, 64));
            v = fmaxf(v, __shfl_xor(v, 4, 64));
            v = fmaxf(v, __shfl_xor(v, 8, 64));
            float m_new = fmaxf(m_i[r], v);
            alpha[r] = __expf(m_i[r] - m_new);
            m_i[r] = m_new;
        }
        float rs[4] = {0.f, 0.f, 0.f, 0.f};
        #pragma unroll
        for (int j = 0; j < 4; j++)
            #pragma unroll
            for (int r = 0; r < 4; r++) {
                float p = __expf(s[j][r] - m_i[r]);
                rs[r] += p;
                Pl[wave][(quad * 4 + r) * 64 + j * 16 + lq] = f2b(p);
            }
        #pragma unroll
        for (int r = 0; r < 4; r++) {
            float v = rs[r];
            v += __shfl_xor(v, 1, 64);
            v += __shfl_xor(v, 2, 64);
            v += __shfl_xor(v, 4, 64);
            v += __shfl_xor(v, 8, 64);
            l_i[r] = l_i[r] * alpha[r] + v;
        }
        #pragma unroll
        for (int jj = 0; jj < 8; jj++)
            #pragma unroll
            for (int r = 0; r < 4; r++) o[jj][r] *= alpha[r];
        __syncthreads();
        #pragma unroll
        for (int jj = 0; jj < 8; jj++) {
            #pragma unroll
            for (int kc = 0; kc < 2; kc++) {
                short8 ap = *(const short8*)&Pl[wave][lq * 64 + kc * 32 + quad * 8];
                short8 bv = *(const short8*)&Vt[(jj * 16 + lq) * 72 + kc * 32 + quad * 8];
                o[jj] = __builtin_amdgcn_mfma_f32_16x16x32_bf16(ap, bv, o[jj], 0, 0, 0);
            }
        }
    }
    #pragma unroll
    for (int jj = 0; jj < 8; jj++) {
        int dh = jj * 16 + lq;
        #pragma unroll
        for (int r = 0; r < 4; r++) {
            int row = qt * 64 + wave * 16 + quad * 4 + r;
            float v = o[jj][r] / l_i[r];
            ab[((long)(b * L_ + row)) * DM + h * DH + dh] = f2b(v);
        }
    }
}

// ---------------- output projection: out(4096 x 2048) = ab * wob^T, fp32 out ----------------
__global__ __launch_bounds__(256, 2) void gemm_out_kernel(
        const unsigned short* __restrict__ A,    // ab: 4096 x 2048 bf16
        const unsigned short* __restrict__ Bm,   // wob: 2048 x 2048 bf16 (N x K)
        float* __restrict__ out) {
    __shared__ __align__(16) unsigned short As[128 * 64];
    __shared__ __align__(16) unsigned short Bs[128 * 64];
    const int tid = threadIdx.x;
    const int wave = tid >> 6, lane = tid & 63, quad = lane >> 4, lq = lane & 15;
    const int wm = wave & 1, wn = wave >> 1;
    const int m0 = blockIdx.y * 128, n0 = blockIdx.x * 128;

    f32x4 acc[4][4];
    const f32x4 zero4 = {0.f, 0.f, 0.f, 0.f};
    #pragma unroll
    for (int i = 0; i < 4; i++)
        #pragma unroll
        for (int j = 0; j < 4; j++) acc[i][j] = zero4;

    const int row_l = lane >> 3;
    const int col_l = (lane & 7) * 8;
    for (int k0 = 0; k0 < DM; k0 += 64) {
        __syncthreads();
        #pragma unroll
        for (int c = 0; c < 4; c++) {
            int chunk = wave * 4 + c;
            int row = chunk * 8 + row_l;
            async16(A  + (long)(m0 + row) * DM + k0 + col_l, &As[chunk * 512]);
            async16(Bm + (long)(n0 + row) * DM + k0 + col_l, &Bs[chunk * 512]);
        }
        __syncthreads();
        #pragma unroll
        for (int s = 0; s < 2; s++) {
            const int kk = s * 32 + quad * 8;
            short8 af[4], bf[4];
            #pragma unroll
            for (int i = 0; i < 4; i++)
                af[i] = *(const short8*)&As[(wm * 64 + i * 16 + lq) * 64 + kk];
            #pragma unroll
            for (int j = 0; j < 4; j++)
                bf[j] = *(const short8*)&Bs[(wn * 64 + j * 16 + lq) * 64 + kk];
            #pragma unroll
            for (int i = 0; i < 4; i++)
                #pragma unroll
                for (int j = 0; j < 4; j++)
                    acc[i][j] = __builtin_amdgcn_mfma_f32_16x16x32_bf16(af[i], bf[j], acc[i][j], 0, 0, 0);
        }
    }
    #pragma unroll
    for (int i = 0; i < 4; i++) {
        #pragma unroll
        for (int j = 0; j < 4; j++) {
            int n = n0 + wn * 64 + j * 16 + lq;
            #pragma unroll
            for (int r = 0; r < 4; r++) {
                int m = m0 + wm * 64 + i * 16 + quad * 4 + r;
                out[(long)m * DM + n] = acc[i][j][r];
            }
        }
    }
}

extern "C" void kernel_launch(void* const* d_in, const int* in_sizes, int n_in,
                              void* d_out, int out_size, void* d_ws, size_t ws_size,
                              hipStream_t stream) {
    (void)in_sizes; (void)n_in; (void)out_size; (void)ws_size;
    const float* x  = (const float*)d_in[0];
    // d_in[1] = mask (causal tril) -- enforced analytically
    const int* tp   = (const int*)d_in[2];
    const float* wq = (const float*)d_in[3];
    const float* wk = (const float*)d_in[4];
    const float* wv = (const float*)d_in[5];
    const float* wo = (const float*)d_in[6];

    char* ws = (char*)d_ws;
    unsigned short* xb   = (unsigned short*)(ws);                // 16 MiB
    unsigned short* wqkv = (unsigned short*)(ws + 16777216L);    // 24 MiB
    unsigned short* wob  = (unsigned short*)(ws + 41943040L);    // 8 MiB
    unsigned short* qb   = (unsigned short*)(ws + 50331648L);    // 16 MiB
    unsigned short* kb   = (unsigned short*)(ws + 67108864L);    // 16 MiB
    unsigned short* vb   = (unsigned short*)(ws + 83886080L);    // 16 MiB
    unsigned short* ab   = (unsigned short*)(ws + 100663296L);   // 16 MiB
    float* out = (float*)d_out;

    cvt_kernel<<<2048, 256, 0, stream>>>(x, wq, wk, wv, wo, xb, wqkv, wob);
    gemm_qkv_kernel<<<dim3(48, 32), 256, 0, stream>>>(xb, wqkv, qb, kb, vb);
    rope_kernel<<<2048, 256, 0, stream>>>(qb, kb, tp);
    attn_kernel<<<dim3(32, 32), 256, 0, stream>>>(qb, kb, vb, ab);
    gemm_out_kernel<<<dim3(16, 32), 256, 0, stream>>>(ab, wob, out);
}

// Round 2
// 459.465 us; speedup vs baseline: 1.3722x; 1.3722x over previous
//
#include <hip/hip_runtime.h>

#define B_   2
#define L_   2048
#define DM   2048
#define H_   16
#define DH   128
#define M_   (B_*L_)        // 4096
#define NQKV (3*DM)         // 6144

typedef __attribute__((ext_vector_type(8))) short short8;
typedef __attribute__((ext_vector_type(4))) float f32x4;
typedef __attribute__((ext_vector_type(4))) unsigned short ushort4_t;

static __device__ __forceinline__ unsigned short f2b(float f) {
    union { float f; unsigned int u; } v; v.f = f;
    unsigned int u = v.u + 0x7fffu + ((v.u >> 16) & 1u);
    return (unsigned short)(u >> 16);
}
static __device__ __forceinline__ float b2f(unsigned short s) {
    union { unsigned int u; float f; } v; v.u = ((unsigned int)s) << 16;
    return v.f;
}
static __device__ __forceinline__ void async16(const void* g, void* l) {
    __builtin_amdgcn_global_load_lds(
        (const __attribute__((address_space(1))) unsigned int*)g,
        (__attribute__((address_space(3))) unsigned int*)l, 16, 0, 0);
}

// ---------------- fp32 -> bf16 conversion of x, Wq|Wk|Wv (concat), Wo ----------------
__global__ void cvt_kernel(const float* __restrict__ x,
                           const float* __restrict__ wq, const float* __restrict__ wk,
                           const float* __restrict__ wv, const float* __restrict__ wo,
                           unsigned short* __restrict__ xb,
                           unsigned short* __restrict__ wqkv,
                           unsigned short* __restrict__ wob) {
    const long MD = (long)M_ * DM;       // 8,388,608
    const long DD = (long)DM * DM;       // 4,194,304
    const long total4 = (MD + 4 * DD) / 4;
    for (long i = (long)blockIdx.x * blockDim.x + threadIdx.x; i < total4;
         i += (long)gridDim.x * blockDim.x) {
        long base = i * 4;
        const float* src; unsigned short* dst;
        if (base < MD) { src = x + base; dst = xb + base; }
        else {
            long r = base - MD;
            int w = (int)(r / DD);
            long off = r - (long)w * DD;
            src = (w == 0 ? wq : (w == 1 ? wk : (w == 2 ? wv : wo))) + off;
            dst = (w < 3) ? (wqkv + r) : (wob + off);
        }
        float4 v = *(const float4*)src;
        ushort4_t o;
        o.x = f2b(v.x); o.y = f2b(v.y); o.z = f2b(v.z); o.w = f2b(v.w);
        *(ushort4_t*)dst = o;
    }
}

// ---------------- QKV projection GEMM: C(4096 x 6144) = xb * wqkv^T ----------------
// epilogue scatters bf16 into qb/kb [b,h,l,dh]; V is written TRANSPOSED: vb[b,h,dh,l]
__global__ __launch_bounds__(256, 2) void gemm_qkv_kernel(
        const unsigned short* __restrict__ A,    // 4096 x 2048 bf16
        const unsigned short* __restrict__ Bm,   // 6144 x 2048 bf16 (N x K, row-major)
        unsigned short* __restrict__ qb, unsigned short* __restrict__ kb,
        unsigned short* __restrict__ vb) {
    __shared__ __align__(16) unsigned short As[128 * 64];
    __shared__ __align__(16) unsigned short Bs[128 * 64];
    const int tid = threadIdx.x;
    const int wave = tid >> 6, lane = tid & 63, quad = lane >> 4, lq = lane & 15;
    const int wm = wave & 1, wn = wave >> 1;
    const int m0 = blockIdx.y * 128, n0 = blockIdx.x * 128;

    f32x4 acc[4][4];
    const f32x4 zero4 = {0.f, 0.f, 0.f, 0.f};
    #pragma unroll
    for (int i = 0; i < 4; i++)
        #pragma unroll
        for (int j = 0; j < 4; j++) acc[i][j] = zero4;

    const int row_l = lane >> 3;
    const int col_l = (lane & 7) * 8;
    for (int k0 = 0; k0 < DM; k0 += 64) {
        __syncthreads();
        #pragma unroll
        for (int c = 0; c < 4; c++) {
            int chunk = wave * 4 + c;
            int row = chunk * 8 + row_l;
            async16(A  + (long)(m0 + row) * DM + k0 + col_l, &As[chunk * 512]);
            async16(Bm + (long)(n0 + row) * DM + k0 + col_l, &Bs[chunk * 512]);
        }
        __syncthreads();
        #pragma unroll
        for (int s = 0; s < 2; s++) {
            const int kk = s * 32 + quad * 8;
            short8 af[4], bf[4];
            #pragma unroll
            for (int i = 0; i < 4; i++)
                af[i] = *(const short8*)&As[(wm * 64 + i * 16 + lq) * 64 + kk];
            #pragma unroll
            for (int j = 0; j < 4; j++)
                bf[j] = *(const short8*)&Bs[(wn * 64 + j * 16 + lq) * 64 + kk];
            #pragma unroll
            for (int i = 0; i < 4; i++)
                #pragma unroll
                for (int j = 0; j < 4; j++)
                    acc[i][j] = __builtin_amdgcn_mfma_f32_16x16x32_bf16(af[i], bf[j], acc[i][j], 0, 0, 0);
        }
    }
    const int which = n0 >> 11;                 // 0=Q, 1=K, 2=V (128 | 2048 so no crossing)
    #pragma unroll
    for (int i = 0; i < 4; i++) {
        #pragma unroll
        for (int j = 0; j < 4; j++) {
            int n = n0 + wn * 64 + j * 16 + lq;
            int oo = n & (DM - 1);
            int h = oo >> 7, dh = oo & 127;
            #pragma unroll
            for (int r = 0; r < 4; r++) {
                int m = m0 + wm * 64 + i * 16 + quad * 4 + r;
                int b = m >> 11, l = m & (L_ - 1);
                unsigned short val = f2b(acc[i][j][r]);
                if (which == 0)
                    qb[((long)(b * H_ + h) * L_ + l) * DH + dh] = val;
                else if (which == 1)
                    kb[((long)(b * H_ + h) * L_ + l) * DH + dh] = val;
                else
                    vb[((long)(b * H_ + h) * DH + dh) * L_ + l] = val;
            }
        }
    }
}

// ---------------- RoPE in-place on qb and kb ----------------
__global__ void rope_kernel(unsigned short* __restrict__ qb,
                            unsigned short* __restrict__ kb,
                            const int* __restrict__ tp) {
    const long PAIRS = (long)B_ * H_ * L_ * (DH / 2);   // 4,194,304
    const float lg = 0.20762050593046016f;               // log2(10000)/64
    for (long i = (long)blockIdx.x * blockDim.x + threadIdx.x; i < 2 * PAIRS;
         i += (long)gridDim.x * blockDim.x) {
        unsigned short* base = (i < PAIRS) ? qb : kb;
        long p = (i < PAIRS) ? i : i - PAIRS;
        int c  = (int)(p & 63);
        int l  = (int)((p >> 6) & (L_ - 1));
        int bh = (int)(p >> 17);
        int b  = bh >> 4;
        int pos = tp[b * L_ + l];
        float ang = (float)pos * exp2f(-lg * (float)c);
        float sn = sinf(ang), cs = cosf(ang);
        unsigned int* pp = (unsigned int*)base + p;
        unsigned int val = *pp;
        float x1 = b2f((unsigned short)(val & 0xffffu));
        float x2 = b2f((unsigned short)(val >> 16));
        float o1 = x1 * cs - x2 * sn;
        float o2 = x1 * sn + x2 * cs;
        *pp = (unsigned int)f2b(o1) | ((unsigned int)f2b(o2) << 16);
    }
}

// ---------------- flash attention (causal), MFMA ----------------
// grid: (B*H, 16); block 256 = 4 waves. Each block handles q-tiles {p, 31-p}
// (uniform 33 kt-iterations). V input is pre-transposed [b,h,dh,l].
__global__ __launch_bounds__(256, 2) void attn_kernel(
        const unsigned short* __restrict__ qb,
        const unsigned short* __restrict__ kb,
        const unsigned short* __restrict__ vbt,   // [b,h,dh,l]
        unsigned short* __restrict__ ab) {
    __shared__ __align__(16) unsigned short Ks[64 * 136];   // padded: 68 dw ≡ 4 (mod 32)
    __shared__ __align__(16) unsigned short Vt[128 * 72];   // padded: 36 dw ≡ 4 (mod 32)
    __shared__ __align__(16) unsigned short Pl[4][16 * 72];
    const int tid = threadIdx.x;
    const int wave = tid >> 6, lane = tid & 63, quad = lane >> 4, lq = lane & 15;
    const int bh = blockIdx.x;
    const int b = bh >> 4, h = bh & 15;
    const long plane = (long)bh * L_ * DH;
    const float scale = 0.08838834764831845f;   // 1/sqrt(128)
    const f32x4 zero4 = {0.f, 0.f, 0.f, 0.f};

    #pragma unroll 1
    for (int half = 0; half < 2; half++) {
        const int qt = half ? (31 - (int)blockIdx.y) : (int)blockIdx.y;
        const int qrow = qt * 64 + wave * 16 + lq;
        short8 aQ[4];
        #pragma unroll
        for (int c = 0; c < 4; c++)
            aQ[c] = *(const short8*)(qb + plane + (long)qrow * DH + c * 32 + quad * 8);

        f32x4 o[8];
        #pragma unroll
        for (int jj = 0; jj < 8; jj++) o[jj] = zero4;
        float m_i[4], l_i[4];
        #pragma unroll
        for (int r = 0; r < 4; r++) { m_i[r] = -__builtin_inff(); l_i[r] = 0.0f; }

        // register prefetch of tile 0
        short8 kreg[4], vreg[4];
        #pragma unroll
        for (int c = 0; c < 4; c++) {
            int flat = c * 2048 + tid * 8;
            kreg[c] = *(const short8*)(kb + plane + flat);
            int vr = flat >> 6, vc = flat & 63;
            vreg[c] = *(const short8*)(vbt + plane + (long)vr * L_ + vc);
        }

        #pragma unroll 1
        for (int kt = 0; kt <= qt; kt++) {
            __syncthreads();
            #pragma unroll
            for (int c = 0; c < 4; c++) {
                int flat = c * 2048 + tid * 8;
                int kr = flat >> 7, kc2 = flat & 127;
                *(short8*)&Ks[kr * 136 + kc2] = kreg[c];
                int vr = flat >> 6, vc = flat & 63;
                *(short8*)&Vt[vr * 72 + vc] = vreg[c];
            }
            __syncthreads();
            if (kt < qt) {     // prefetch next tile while computing this one
                const long kbase = plane + (long)(kt + 1) * 64 * DH;
                const int lcol = (kt + 1) * 64;
                #pragma unroll
                for (int c = 0; c < 4; c++) {
                    int flat = c * 2048 + tid * 8;
                    kreg[c] = *(const short8*)(kb + kbase + flat);
                    int vr = flat >> 6, vc = flat & 63;
                    vreg[c] = *(const short8*)(vbt + plane + (long)vr * L_ + lcol + vc);
                }
            }

            // S = Q K^T
            f32x4 s[4];
            #pragma unroll
            for (int j = 0; j < 4; j++) {
                s[j] = zero4;
                #pragma unroll
                for (int c = 0; c < 4; c++) {
                    short8 bk = *(const short8*)&Ks[(j * 16 + lq) * 136 + c * 32 + quad * 8];
                    s[j] = __builtin_amdgcn_mfma_f32_16x16x32_bf16(aQ[c], bk, s[j], 0, 0, 0);
                }
            }
            const bool diag = (kt == qt);
            #pragma unroll
            for (int j = 0; j < 4; j++) {
                int key = kt * 64 + j * 16 + lq;
                #pragma unroll
                for (int r = 0; r < 4; r++) {
                    float v = s[j][r] * scale;
                    int row = qt * 64 + wave * 16 + quad * 4 + r;
                    if (diag && key > row) v = -__builtin_inff();
                    s[j][r] = v;
                }
            }
            float alpha[4];
            #pragma unroll
            for (int r = 0; r < 4; r++) {
                float v = fmaxf(fmaxf(s[0][r], s[1][r]), fmaxf(s[2][r], s[3][r]));
                v = fmaxf(v, __shfl_xor(v, 1, 64));
                v = fmaxf(v, __shfl_xor(v, 2, 64));
                v = fmaxf(v, __shfl_xor(v, 4, 64));
                v = fmaxf(v, __shfl_xor(v, 8, 64));
                float m_new = fmaxf(m_i[r], v);
                alpha[r] = __expf(m_i[r] - m_new);
                m_i[r] = m_new;
            }
            float rs[4] = {0.f, 0.f, 0.f, 0.f};
            #pragma unroll
            for (int j = 0; j < 4; j++)
                #pragma unroll
                for (int r = 0; r < 4; r++) {
                    float p = __expf(s[j][r] - m_i[r]);
                    rs[r] += p;
                    Pl[wave][(quad * 4 + r) * 72 + j * 16 + lq] = f2b(p);
                }
            #pragma unroll
            for (int r = 0; r < 4; r++) {
                float v = rs[r];
                v += __shfl_xor(v, 1, 64);
                v += __shfl_xor(v, 2, 64);
                v += __shfl_xor(v, 4, 64);
                v += __shfl_xor(v, 8, 64);
                l_i[r] = l_i[r] * alpha[r] + v;
            }
            #pragma unroll
            for (int jj = 0; jj < 8; jj++)
                #pragma unroll
                for (int r = 0; r < 4; r++) o[jj][r] *= alpha[r];
            // O += P V  (P from per-wave LDS, no extra barrier needed)
            #pragma unroll
            for (int jj = 0; jj < 8; jj++) {
                #pragma unroll
                for (int kc = 0; kc < 2; kc++) {
                    short8 ap = *(const short8*)&Pl[wave][lq * 72 + kc * 32 + quad * 8];
                    short8 bv = *(const short8*)&Vt[(jj * 16 + lq) * 72 + kc * 32 + quad * 8];
                    o[jj] = __builtin_amdgcn_mfma_f32_16x16x32_bf16(ap, bv, o[jj], 0, 0, 0);
                }
            }
        }
        #pragma unroll
        for (int jj = 0; jj < 8; jj++) {
            int dh = jj * 16 + lq;
            #pragma unroll
            for (int r = 0; r < 4; r++) {
                int row = qt * 64 + wave * 16 + quad * 4 + r;
                float v = o[jj][r] / l_i[r];
                ab[((long)(b * L_ + row)) * DM + h * DH + dh] = f2b(v);
            }
        }
    }
}

// ---------------- output projection: out(4096 x 2048) = ab * wob^T, fp32 out ----------------
__global__ __launch_bounds__(256, 2) void gemm_out_kernel(
        const unsigned short* __restrict__ A,    // ab: 4096 x 2048 bf16
        const unsigned short* __restrict__ Bm,   // wob: 2048 x 2048 bf16 (N x K)
        float* __restrict__ out) {
    __shared__ __align__(16) unsigned short As[128 * 64];
    __shared__ __align__(16) unsigned short Bs[128 * 64];
    const int tid = threadIdx.x;
    const int wave = tid >> 6, lane = tid & 63, quad = lane >> 4, lq = lane & 15;
    const int wm = wave & 1, wn = wave >> 1;
    const int m0 = blockIdx.y * 128, n0 = blockIdx.x * 128;

    f32x4 acc[4][4];
    const f32x4 zero4 = {0.f, 0.f, 0.f, 0.f};
    #pragma unroll
    for (int i = 0; i < 4; i++)
        #pragma unroll
        for (int j = 0; j < 4; j++) acc[i][j] = zero4;

    const int row_l = lane >> 3;
    const int col_l = (lane & 7) * 8;
    for (int k0 = 0; k0 < DM; k0 += 64) {
        __syncthreads();
        #pragma unroll
        for (int c = 0; c < 4; c++) {
            int chunk = wave * 4 + c;
            int row = chunk * 8 + row_l;
            async16(A  + (long)(m0 + row) * DM + k0 + col_l, &As[chunk * 512]);
            async16(Bm + (long)(n0 + row) * DM + k0 + col_l, &Bs[chunk * 512]);
        }
        __syncthreads();
        #pragma unroll
        for (int s = 0; s < 2; s++) {
            const int kk = s * 32 + quad * 8;
            short8 af[4], bf[4];
            #pragma unroll
            for (int i = 0; i < 4; i++)
                af[i] = *(const short8*)&As[(wm * 64 + i * 16 + lq) * 64 + kk];
            #pragma unroll
            for (int j = 0; j < 4; j++)
                bf[j] = *(const short8*)&Bs[(wn * 64 + j * 16 + lq) * 64 + kk];
            #pragma unroll
            for (int i = 0; i < 4; i++)
                #pragma unroll
                for (int j = 0; j < 4; j++)
                    acc[i][j] = __builtin_amdgcn_mfma_f32_16x16x32_bf16(af[i], bf[j], acc[i][j], 0, 0, 0);
        }
    }
    #pragma unroll
    for (int i = 0; i < 4; i++) {
        #pragma unroll
        for (int j = 0; j < 4; j++) {
            int n = n0 + wn * 64 + j * 16 + lq;
            #pragma unroll
            for (int r = 0; r < 4; r++) {
                int m = m0 + wm * 64 + i * 16 + quad * 4 + r;
                out[(long)m * DM + n] = acc[i][j][r];
            }
        }
    }
}

extern "C" void kernel_launch(void* const* d_in, const int* in_sizes, int n_in,
                              void* d_out, int out_size, void* d_ws, size_t ws_size,
                              hipStream_t stream) {
    (void)in_sizes; (void)n_in; (void)out_size; (void)ws_size;
    const float* x  = (const float*)d_in[0];
    // d_in[1] = mask (causal tril) -- enforced analytically
    const int* tp   = (const int*)d_in[2];
    const float* wq = (const float*)d_in[3];
    const float* wk = (const float*)d_in[4];
    const float* wv = (const float*)d_in[5];
    const float* wo = (const float*)d_in[6];

    char* ws = (char*)d_ws;
    unsigned short* xb   = (unsigned short*)(ws);                // 16 MiB
    unsigned short* wqkv = (unsigned short*)(ws + 16777216L);    // 24 MiB
    unsigned short* wob  = (unsigned short*)(ws + 41943040L);    // 8 MiB
    unsigned short* qb   = (unsigned short*)(ws + 50331648L);    // 16 MiB
    unsigned short* kb   = (unsigned short*)(ws + 67108864L);    // 16 MiB
    unsigned short* vbt  = (unsigned short*)(ws + 83886080L);    // 16 MiB [b,h,dh,l]
    unsigned short* ab   = (unsigned short*)(ws + 100663296L);   // 16 MiB
    float* out = (float*)d_out;

    cvt_kernel<<<2048, 256, 0, stream>>>(x, wq, wk, wv, wo, xb, wqkv, wob);
    gemm_qkv_kernel<<<dim3(48, 32), 256, 0, stream>>>(xb, wqkv, qb, kb, vbt);
    rope_kernel<<<2048, 256, 0, stream>>>(qb, kb, tp);
    attn_kernel<<<dim3(32, 16), 256, 0, stream>>>(qb, kb, vbt, ab);
    gemm_out_kernel<<<dim3(16, 32), 256, 0, stream>>>(ab, wob, out);
}

// Round 3
// 450.326 us; speedup vs baseline: 1.4000x; 1.0203x over previous
//
#include <hip/hip_runtime.h>

#define B_   2
#define L_   2048
#define DM   2048
#define H_   16
#define DH   128
#define M_   (B_*L_)        // 4096
#define NQKV (3*DM)         // 6144

typedef __attribute__((ext_vector_type(8))) short short8;
typedef __attribute__((ext_vector_type(4))) float f32x4;
typedef __attribute__((ext_vector_type(4))) unsigned short ushort4_t;

static __device__ __forceinline__ unsigned short f2b(float f) {
    union { float f; unsigned int u; } v; v.f = f;
    unsigned int u = v.u + 0x7fffu + ((v.u >> 16) & 1u);
    return (unsigned short)(u >> 16);
}
static __device__ __forceinline__ float b2f(unsigned short s) {
    union { unsigned int u; float f; } v; v.u = ((unsigned int)s) << 16;
    return v.f;
}
static __device__ __forceinline__ void async16(const void* g, void* l) {
    __builtin_amdgcn_global_load_lds(
        (const __attribute__((address_space(1))) unsigned int*)g,
        (__attribute__((address_space(3))) unsigned int*)l, 16, 0, 0);
}

// ---------------- fp32 -> bf16 conversion + rope cos/sin table ----------------
__global__ void cvt_kernel(const float* __restrict__ x,
                           const float* __restrict__ wq, const float* __restrict__ wk,
                           const float* __restrict__ wv, const float* __restrict__ wo,
                           unsigned short* __restrict__ xb,
                           unsigned short* __restrict__ wqkv,
                           unsigned short* __restrict__ wob,
                           float2* __restrict__ tab, int use_tab) {
    const long MD = (long)M_ * DM;       // 8,388,608
    const long DD = (long)DM * DM;       // 4,194,304
    const long total4 = (MD + 4 * DD) / 4;
    for (long i = (long)blockIdx.x * blockDim.x + threadIdx.x; i < total4;
         i += (long)gridDim.x * blockDim.x) {
        long base = i * 4;
        const float* src; unsigned short* dst;
        if (base < MD) { src = x + base; dst = xb + base; }
        else {
            long r = base - MD;
            int w = (int)(r / DD);
            long off = r - (long)w * DD;
            src = (w == 0 ? wq : (w == 1 ? wk : (w == 2 ? wv : wo))) + off;
            dst = (w < 3) ? (wqkv + r) : (wob + off);
        }
        float4 v = *(const float4*)src;
        ushort4_t o;
        o.x = f2b(v.x); o.y = f2b(v.y); o.z = f2b(v.z); o.w = f2b(v.w);
        *(ushort4_t*)dst = o;
    }
    if (use_tab) {
        const float lg = 0.20762050593046016f;   // log2(10000)/64
        for (int i = blockIdx.x * blockDim.x + threadIdx.x; i < L_ * 64;
             i += gridDim.x * blockDim.x) {
            int pos = i >> 6, c = i & 63;
            float ang = (float)pos * exp2f(-lg * (float)c);
            float2 cs; cs.x = cosf(ang); cs.y = sinf(ang);
            tab[i] = cs;
        }
    }
}

// ---------------- QKV projection GEMM: C(4096 x 6144) = xb * wqkv^T ----------------
// LDS XOR-swizzled (colgroup ^= row&7) to kill ds_read_b128 bank conflicts.
// epilogue scatters bf16 into qb/kb [b,h,l,dh]; V written TRANSPOSED vb[b,h,dh,l]
__global__ __launch_bounds__(256, 2) void gemm_qkv_kernel(
        const unsigned short* __restrict__ A,    // 4096 x 2048 bf16
        const unsigned short* __restrict__ Bm,   // 6144 x 2048 bf16 (N x K, row-major)
        unsigned short* __restrict__ qb, unsigned short* __restrict__ kb,
        unsigned short* __restrict__ vb) {
    __shared__ __align__(16) unsigned short As[128 * 64];
    __shared__ __align__(16) unsigned short Bs[128 * 64];
    const int tid = threadIdx.x;
    const int wave = tid >> 6, lane = tid & 63, quad = lane >> 4, lq = lane & 15;
    const int wm = wave & 1, wn = wave >> 1;
    const int m0 = blockIdx.y * 128, n0 = blockIdx.x * 128;

    f32x4 acc[4][4];
    const f32x4 zero4 = {0.f, 0.f, 0.f, 0.f};
    #pragma unroll
    for (int i = 0; i < 4; i++)
        #pragma unroll
        for (int j = 0; j < 4; j++) acc[i][j] = zero4;

    const int row_l = lane >> 3;
    const int col_l = (((lane & 7) ^ row_l) * 8);   // XOR swizzle on source column
    for (int k0 = 0; k0 < DM; k0 += 64) {
        __syncthreads();
        #pragma unroll
        for (int c = 0; c < 4; c++) {
            int chunk = wave * 4 + c;
            int row = chunk * 8 + row_l;
            async16(A  + (long)(m0 + row) * DM + k0 + col_l, &As[chunk * 512]);
            async16(Bm + (long)(n0 + row) * DM + k0 + col_l, &Bs[chunk * 512]);
        }
        __syncthreads();
        #pragma unroll
        for (int s = 0; s < 2; s++) {
            const int cg = ((s * 4 + quad) ^ (lq & 7)) * 8;   // swizzled read
            short8 af[4], bf[4];
            #pragma unroll
            for (int i = 0; i < 4; i++)
                af[i] = *(const short8*)&As[(wm * 64 + i * 16 + lq) * 64 + cg];
            #pragma unroll
            for (int j = 0; j < 4; j++)
                bf[j] = *(const short8*)&Bs[(wn * 64 + j * 16 + lq) * 64 + cg];
            #pragma unroll
            for (int i = 0; i < 4; i++)
                #pragma unroll
                for (int j = 0; j < 4; j++)
                    acc[i][j] = __builtin_amdgcn_mfma_f32_16x16x32_bf16(af[i], bf[j], acc[i][j], 0, 0, 0);
        }
    }
    const int which = n0 >> 11;                 // 0=Q, 1=K, 2=V (128 | 2048 so no crossing)
    #pragma unroll
    for (int i = 0; i < 4; i++) {
        #pragma unroll
        for (int j = 0; j < 4; j++) {
            int n = n0 + wn * 64 + j * 16 + lq;
            int oo = n & (DM - 1);
            int h = oo >> 7, dh = oo & 127;
            #pragma unroll
            for (int r = 0; r < 4; r++) {
                int m = m0 + wm * 64 + i * 16 + quad * 4 + r;
                int b = m >> 11, l = m & (L_ - 1);
                unsigned short val = f2b(acc[i][j][r]);
                if (which == 0)
                    qb[((long)(b * H_ + h) * L_ + l) * DH + dh] = val;
                else if (which == 1)
                    kb[((long)(b * H_ + h) * L_ + l) * DH + dh] = val;
                else
                    vb[((long)(b * H_ + h) * DH + dh) * L_ + l] = val;
            }
        }
    }
}

// ---------------- RoPE in-place on qb and kb ----------------
__global__ void rope_kernel(unsigned short* __restrict__ qb,
                            unsigned short* __restrict__ kb,
                            const int* __restrict__ tp,
                            const float2* __restrict__ tab, int use_tab) {
    const long PAIRS = (long)B_ * H_ * L_ * (DH / 2);   // 4,194,304
    const float lg = 0.20762050593046016f;               // log2(10000)/64
    for (long i = (long)blockIdx.x * blockDim.x + threadIdx.x; i < 2 * PAIRS;
         i += (long)gridDim.x * blockDim.x) {
        unsigned short* base = (i < PAIRS) ? qb : kb;
        long p = (i < PAIRS) ? i : i - PAIRS;
        int c  = (int)(p & 63);
        int l  = (int)((p >> 6) & (L_ - 1));
        int bh = (int)(p >> 17);
        int b  = bh >> 4;
        int pos = tp[b * L_ + l];
        float sn, cs;
        if (use_tab && pos < L_) {
            float2 t = tab[(pos << 6) + c];
            cs = t.x; sn = t.y;
        } else {
            float ang = (float)pos * exp2f(-lg * (float)c);
            sn = sinf(ang); cs = cosf(ang);
        }
        unsigned int* pp = (unsigned int*)base + p;
        unsigned int val = *pp;
        float x1 = b2f((unsigned short)(val & 0xffffu));
        float x2 = b2f((unsigned short)(val >> 16));
        float o1 = x1 * cs - x2 * sn;
        float o2 = x1 * sn + x2 * cs;
        *pp = (unsigned int)f2b(o1) | ((unsigned int)f2b(o2) << 16);
    }
}

// ---------------- flash attention (causal), MFMA ----------------
// grid: (B*H, 32); one 64-row q-tile per block, longest-first (qt = 31 - y).
// V input pre-transposed [b,h,dh,l]. exp2-domain softmax; P truncated to bf16
// consistently in numerator and denominator.
__global__ __launch_bounds__(256, 2) void attn_kernel(
        const unsigned short* __restrict__ qb,
        const unsigned short* __restrict__ kb,
        const unsigned short* __restrict__ vbt,   // [b,h,dh,l]
        unsigned short* __restrict__ ab) {
    __shared__ __align__(16) unsigned short Ks[64 * 136];   // padded: 68 dw ≡ 4 (mod 32)
    __shared__ __align__(16) unsigned short Vt[128 * 72];   // padded: 36 dw ≡ 4 (mod 32)
    __shared__ __align__(16) unsigned short Pl[4][16 * 72];
    const int tid = threadIdx.x;
    const int wave = tid >> 6, lane = tid & 63, quad = lane >> 4, lq = lane & 15;
    const int bh = blockIdx.x;
    const int b = bh >> 4, h = bh & 15;
    const long plane = (long)bh * L_ * DH;
    const float scale2 = 0.08838834764831845f * 1.44269504088896f;  // 1/sqrt(128)*log2(e)
    const f32x4 zero4 = {0.f, 0.f, 0.f, 0.f};

    const int qt = 31 - (int)blockIdx.y;     // longest blocks dispatch first
    const int qrow = qt * 64 + wave * 16 + lq;
    short8 aQ[4];
    #pragma unroll
    for (int c = 0; c < 4; c++)
        aQ[c] = *(const short8*)(qb + plane + (long)qrow * DH + c * 32 + quad * 8);

    f32x4 o[8];
    #pragma unroll
    for (int jj = 0; jj < 8; jj++) o[jj] = zero4;
    float m_i[4], l_i[4];
    #pragma unroll
    for (int r = 0; r < 4; r++) { m_i[r] = -__builtin_inff(); l_i[r] = 0.0f; }

    // register prefetch of tile 0
    short8 kreg[4], vreg[4];
    #pragma unroll
    for (int c = 0; c < 4; c++) {
        int flat = c * 2048 + tid * 8;
        kreg[c] = *(const short8*)(kb + plane + flat);
        int vr = flat >> 6, vc = flat & 63;
        vreg[c] = *(const short8*)(vbt + plane + (long)vr * L_ + vc);
    }

    #pragma unroll 1
    for (int kt = 0; kt <= qt; kt++) {
        __syncthreads();
        #pragma unroll
        for (int c = 0; c < 4; c++) {
            int flat = c * 2048 + tid * 8;
            int kr = flat >> 7, kc2 = flat & 127;
            *(short8*)&Ks[kr * 136 + kc2] = kreg[c];
            int vr = flat >> 6, vc = flat & 63;
            *(short8*)&Vt[vr * 72 + vc] = vreg[c];
        }
        __syncthreads();
        if (kt < qt) {     // prefetch next tile while computing this one
            const long kbase = plane + (long)(kt + 1) * 64 * DH;
            const int lcol = (kt + 1) * 64;
            #pragma unroll
            for (int c = 0; c < 4; c++) {
                int flat = c * 2048 + tid * 8;
                kreg[c] = *(const short8*)(kb + kbase + flat);
                int vr = flat >> 6, vc = flat & 63;
                vreg[c] = *(const short8*)(vbt + plane + (long)vr * L_ + lcol + vc);
            }
        }

        // S = Q K^T (exp2 domain)
        f32x4 s[4];
        #pragma unroll
        for (int j = 0; j < 4; j++) {
            s[j] = zero4;
            #pragma unroll
            for (int c = 0; c < 4; c++) {
                short8 bk = *(const short8*)&Ks[(j * 16 + lq) * 136 + c * 32 + quad * 8];
                s[j] = __builtin_amdgcn_mfma_f32_16x16x32_bf16(aQ[c], bk, s[j], 0, 0, 0);
            }
        }
        const bool diag = (kt == qt);
        #pragma unroll
        for (int j = 0; j < 4; j++) {
            int key = kt * 64 + j * 16 + lq;
            #pragma unroll
            for (int r = 0; r < 4; r++) {
                float v = s[j][r] * scale2;
                int row = qt * 64 + wave * 16 + quad * 4 + r;
                if (diag && key > row) v = -__builtin_inff();
                s[j][r] = v;
            }
        }
        float alpha[4];
        #pragma unroll
        for (int r = 0; r < 4; r++) {
            float v = fmaxf(fmaxf(s[0][r], s[1][r]), fmaxf(s[2][r], s[3][r]));
            v = fmaxf(v, __shfl_xor(v, 1, 64));
            v = fmaxf(v, __shfl_xor(v, 2, 64));
            v = fmaxf(v, __shfl_xor(v, 4, 64));
            v = fmaxf(v, __shfl_xor(v, 8, 64));
            float m_new = fmaxf(m_i[r], v);
            alpha[r] = exp2f(m_i[r] - m_new);
            m_i[r] = m_new;
        }
        float rs[4] = {0.f, 0.f, 0.f, 0.f};
        #pragma unroll
        for (int j = 0; j < 4; j++)
            #pragma unroll
            for (int r = 0; r < 4; r++) {
                float p = exp2f(s[j][r] - m_i[r]);
                unsigned int ub = __builtin_bit_cast(unsigned int, p) & 0xffff0000u;
                rs[r] += __builtin_bit_cast(float, ub);       // sum truncated value
                Pl[wave][(quad * 4 + r) * 72 + j * 16 + lq] = (unsigned short)(ub >> 16);
            }
        #pragma unroll
        for (int r = 0; r < 4; r++) {
            float v = rs[r];
            v += __shfl_xor(v, 1, 64);
            v += __shfl_xor(v, 2, 64);
            v += __shfl_xor(v, 4, 64);
            v += __shfl_xor(v, 8, 64);
            l_i[r] = l_i[r] * alpha[r] + v;
        }
        #pragma unroll
        for (int jj = 0; jj < 8; jj++)
            #pragma unroll
            for (int r = 0; r < 4; r++) o[jj][r] *= alpha[r];
        // O += P V  (P from per-wave LDS, no extra barrier needed)
        #pragma unroll
        for (int jj = 0; jj < 8; jj++) {
            #pragma unroll
            for (int kc = 0; kc < 2; kc++) {
                short8 ap = *(const short8*)&Pl[wave][lq * 72 + kc * 32 + quad * 8];
                short8 bv = *(const short8*)&Vt[(jj * 16 + lq) * 72 + kc * 32 + quad * 8];
                o[jj] = __builtin_amdgcn_mfma_f32_16x16x32_bf16(ap, bv, o[jj], 0, 0, 0);
            }
        }
    }
    #pragma unroll
    for (int jj = 0; jj < 8; jj++) {
        int dh = jj * 16 + lq;
        #pragma unroll
        for (int r = 0; r < 4; r++) {
            int row = qt * 64 + wave * 16 + quad * 4 + r;
            float v = o[jj][r] / l_i[r];
            ab[((long)(b * L_ + row)) * DM + h * DH + dh] = f2b(v);
        }
    }
}

// ---------------- output projection: out(4096 x 2048) = ab * wob^T, fp32 out ----------------
__global__ __launch_bounds__(256, 2) void gemm_out_kernel(
        const unsigned short* __restrict__ A,    // ab: 4096 x 2048 bf16
        const unsigned short* __restrict__ Bm,   // wob: 2048 x 2048 bf16 (N x K)
        float* __restrict__ out) {
    __shared__ __align__(16) unsigned short As[128 * 64];
    __shared__ __align__(16) unsigned short Bs[128 * 64];
    const int tid = threadIdx.x;
    const int wave = tid >> 6, lane = tid & 63, quad = lane >> 4, lq = lane & 15;
    const int wm = wave & 1, wn = wave >> 1;
    const int m0 = blockIdx.y * 128, n0 = blockIdx.x * 128;

    f32x4 acc[4][4];
    const f32x4 zero4 = {0.f, 0.f, 0.f, 0.f};
    #pragma unroll
    for (int i = 0; i < 4; i++)
        #pragma unroll
        for (int j = 0; j < 4; j++) acc[i][j] = zero4;

    const int row_l = lane >> 3;
    const int col_l = (((lane & 7) ^ row_l) * 8);   // XOR swizzle on source column
    for (int k0 = 0; k0 < DM; k0 += 64) {
        __syncthreads();
        #pragma unroll
        for (int c = 0; c < 4; c++) {
            int chunk = wave * 4 + c;
            int row = chunk * 8 + row_l;
            async16(A  + (long)(m0 + row) * DM + k0 + col_l, &As[chunk * 512]);
            async16(Bm + (long)(n0 + row) * DM + k0 + col_l, &Bs[chunk * 512]);
        }
        __syncthreads();
        #pragma unroll
        for (int s = 0; s < 2; s++) {
            const int cg = ((s * 4 + quad) ^ (lq & 7)) * 8;   // swizzled read
            short8 af[4], bf[4];
            #pragma unroll
            for (int i = 0; i < 4; i++)
                af[i] = *(const short8*)&As[(wm * 64 + i * 16 + lq) * 64 + cg];
            #pragma unroll
            for (int j = 0; j < 4; j++)
                bf[j] = *(const short8*)&Bs[(wn * 64 + j * 16 + lq) * 64 + cg];
            #pragma unroll
            for (int i = 0; i < 4; i++)
                #pragma unroll
                for (int j = 0; j < 4; j++)
                    acc[i][j] = __builtin_amdgcn_mfma_f32_16x16x32_bf16(af[i], bf[j], acc[i][j], 0, 0, 0);
        }
    }
    #pragma unroll
    for (int i = 0; i < 4; i++) {
        #pragma unroll
        for (int j = 0; j < 4; j++) {
            int n = n0 + wn * 64 + j * 16 + lq;
            #pragma unroll
            for (int r = 0; r < 4; r++) {
                int m = m0 + wm * 64 + i * 16 + quad * 4 + r;
                out[(long)m * DM + n] = acc[i][j][r];
            }
        }
    }
}

extern "C" void kernel_launch(void* const* d_in, const int* in_sizes, int n_in,
                              void* d_out, int out_size, void* d_ws, size_t ws_size,
                              hipStream_t stream) {
    (void)in_sizes; (void)n_in; (void)out_size;
    const float* x  = (const float*)d_in[0];
    // d_in[1] = mask (causal tril) -- enforced analytically
    const int* tp   = (const int*)d_in[2];
    const float* wq = (const float*)d_in[3];
    const float* wk = (const float*)d_in[4];
    const float* wv = (const float*)d_in[5];
    const float* wo = (const float*)d_in[6];

    char* ws = (char*)d_ws;
    unsigned short* xb   = (unsigned short*)(ws);                // 16 MiB
    unsigned short* wqkv = (unsigned short*)(ws + 16777216L);    // 24 MiB
    unsigned short* wob  = (unsigned short*)(ws + 41943040L);    // 8 MiB
    unsigned short* qb   = (unsigned short*)(ws + 50331648L);    // 16 MiB
    unsigned short* kb   = (unsigned short*)(ws + 67108864L);    // 16 MiB
    unsigned short* vbt  = (unsigned short*)(ws + 83886080L);    // 16 MiB [b,h,dh,l]
    unsigned short* ab   = (unsigned short*)(ws + 100663296L);   // 16 MiB
    float2* tab          = (float2*)(ws + 117440512L);           // 1 MiB rope table
    const int use_tab = (ws_size >= 117440512UL + (unsigned long)(L_ * 64) * 8UL) ? 1 : 0;
    float* out = (float*)d_out;

    cvt_kernel<<<2048, 256, 0, stream>>>(x, wq, wk, wv, wo, xb, wqkv, wob, tab, use_tab);
    gemm_qkv_kernel<<<dim3(48, 32), 256, 0, stream>>>(xb, wqkv, qb, kb, vbt);
    rope_kernel<<<2048, 256, 0, stream>>>(qb, kb, tp, tab, use_tab);
    attn_kernel<<<dim3(32, 32), 256, 0, stream>>>(qb, kb, vbt, ab);
    gemm_out_kernel<<<dim3(16, 32), 256, 0, stream>>>(ab, wob, out);
}